// Round 12
// baseline (100.217 us; speedup 1.0000x reference)
//
#include <hip/hip_runtime.h>
#include <cstdint>

typedef unsigned short u16;
using bf16x8 = __attribute__((ext_vector_type(8))) short;
using u16x8  = __attribute__((ext_vector_type(8))) unsigned short;
using f32x4  = __attribute__((ext_vector_type(4))) float;

#define DM 1024

__device__ __forceinline__ u16 f2b(float f) {
    union { float f; unsigned u; } v; v.f = f;
    unsigned r = v.u + 0x7FFFu + ((v.u >> 16) & 1u);   // round-to-nearest-even
    return (u16)(r >> 16);
}

__device__ __forceinline__ u16x8 cvt8(f32x4 a, f32x4 b, float sc) {
    u16x8 o;
    o[0] = f2b(a[0] * sc); o[1] = f2b(a[1] * sc);
    o[2] = f2b(a[2] * sc); o[3] = f2b(a[3] * sc);
    o[4] = f2b(b[0] * sc); o[5] = f2b(b[1] * sc);
    o[6] = f2b(b[2] * sc); o[7] = f2b(b[3] * sc);
    return o;
}

#define GLL(gp, lp) __builtin_amdgcn_global_load_lds( \
    (const __attribute__((address_space(1))) void*)(uintptr_t)(gp), \
    (__attribute__((address_space(3))) void*)(unsigned)(uintptr_t)(lp), 16, 0, 0)

#define BAR()    __builtin_amdgcn_s_barrier()
#define WAITV0() asm volatile("s_waitcnt vmcnt(0)" ::: "memory")

// ---------------- qkv GEMM with fused f32->bf16 conversion ----------------
// C[4096][3072] = x @ [Wq;Wk;Wv]^T (bf16 out, stride 3072). Wq pre-scaled 1/8.
// 128x192 tile, BK=64, 512 threads = 8 waves (2M x 4N), wave owns 64x48.
// Staging: reg-stage f32 -> convert -> swizzled ds_write (no GLL, no xb buffer).
#define MROW3(af_, bf_, d) \
    acc[d][0] = __builtin_amdgcn_mfma_f32_16x16x32_bf16(af_, bf_[0], acc[d][0], 0, 0, 0); \
    acc[d][1] = __builtin_amdgcn_mfma_f32_16x16x32_bf16(af_, bf_[1], acc[d][1], 0, 0, 0); \
    acc[d][2] = __builtin_amdgcn_mfma_f32_16x16x32_bf16(af_, bf_[2], acc[d][2], 0, 0, 0);

#define MFMA12(af_, bf_) do { \
    __builtin_amdgcn_s_setprio(1); \
    MROW3(af_[0], bf_, 0) \
    MROW3(af_[1], bf_, 1) \
    MROW3(af_[2], bf_, 2) \
    MROW3(af_[3], bf_, 3) \
    __builtin_amdgcn_s_setprio(0); } while (0)

__global__ __launch_bounds__(512, 2) void gemm_qkv8(const float* __restrict__ x,
                                                    const float* __restrict__ Wq,
                                                    const float* __restrict__ Wk,
                                                    const float* __restrict__ Wv,
                                                    u16* __restrict__ QKV) {
    __shared__ __align__(16) u16 As[2 * 8192];    // 32 KB: [buf][128 rows][64]
    __shared__ __align__(16) u16 Bs[2 * 12288];   // 48 KB: [buf][192 rows][64]
    const int tid  = threadIdx.x;
    const int lane = tid & 63;
    const int wid  = tid >> 6;
    const int wr   = wid >> 2;          // 0..1
    const int wc   = wid & 3;           // 0..3
    const int fr   = lane & 15;
    const int fg   = lane >> 4;

    // 2D XCD-chunked bijective mapping: 32x16 tiles, regions of 4Mx4N.
    const int hw  = blockIdx.y * 16 + blockIdx.x;    // 0..511
    const int xcd = hw & 7;
    const int idx = hw >> 3;
    const int reg = xcd + ((idx >> 4) << 3);
    const int mt  = ((reg >> 2) << 2) + ((idx & 15) >> 2);
    const int nt  = ((reg & 3) << 2) + (idx & 3);
    const int brow = mt << 7;
    const int bcol = nt * 192;

    // staging geometry: thread covers LDS row srow, 8-elem col group cg;
    // dest col-chunk swizzled by (cg ^ (srow&7)) -> same layout GLL+preswizzled-src gave
    const int srow = tid >> 3;          // 0..63
    const int cg   = tid & 7;
    const int aD   = srow * 64 + ((cg ^ (srow & 7)) << 3);   // elem offset within chunk

    const float* aSrc0 = x + (size_t)(brow + srow) * 1024 + cg * 8;
    const float* aSrc1 = x + (size_t)(brow + 64 + srow) * 1024 + cg * 8;
    const float* bSrc0; const float* bSrc1; const float* bSrc2;
    float bScl0, bScl1, bScl2;
    {
        int g0 = bcol + srow, g1 = bcol + 64 + srow, g2 = bcol + 128 + srow;
        bSrc0 = ((g0 < 1024) ? (Wq + (size_t)g0 * 1024)
                 : (g0 < 2048) ? (Wk + (size_t)(g0 - 1024) * 1024)
                               : (Wv + (size_t)(g0 - 2048) * 1024)) + cg * 8;
        bScl0 = (g0 < 1024) ? 0.125f : 1.0f;
        bSrc1 = ((g1 < 1024) ? (Wq + (size_t)g1 * 1024)
                 : (g1 < 2048) ? (Wk + (size_t)(g1 - 1024) * 1024)
                               : (Wv + (size_t)(g1 - 2048) * 1024)) + cg * 8;
        bScl1 = (g1 < 1024) ? 0.125f : 1.0f;
        bSrc2 = ((g2 < 1024) ? (Wq + (size_t)g2 * 1024)
                 : (g2 < 2048) ? (Wk + (size_t)(g2 - 1024) * 1024)
                               : (Wv + (size_t)(g2 - 2048) * 1024)) + cg * 8;
        bScl2 = (g2 < 1024) ? 0.125f : 1.0f;
    }

    f32x4 la00, la01, la10, la11;           // A staging: 2 chunks x 2 f32x4
    f32x4 lb00, lb01, lb10, lb11, lb20, lb21;  // B staging: 3 chunks x 2 f32x4

#define ISSUE(kt) do { \
    la00 = *(const f32x4*)(aSrc0 + (kt) * 64); la01 = *(const f32x4*)(aSrc0 + (kt) * 64 + 4); \
    la10 = *(const f32x4*)(aSrc1 + (kt) * 64); la11 = *(const f32x4*)(aSrc1 + (kt) * 64 + 4); \
    lb00 = *(const f32x4*)(bSrc0 + (kt) * 64); lb01 = *(const f32x4*)(bSrc0 + (kt) * 64 + 4); \
    lb10 = *(const f32x4*)(bSrc1 + (kt) * 64); lb11 = *(const f32x4*)(bSrc1 + (kt) * 64 + 4); \
    lb20 = *(const f32x4*)(bSrc2 + (kt) * 64); lb21 = *(const f32x4*)(bSrc2 + (kt) * 64 + 4); \
} while (0)

#define WRITE(bi) do { \
    u16* Ad = As + (bi) * 8192 + aD; \
    u16* Bd = Bs + (bi) * 12288 + aD; \
    *(u16x8*)(Ad)        = cvt8(la00, la01, 1.0f); \
    *(u16x8*)(Ad + 4096) = cvt8(la10, la11, 1.0f); \
    *(u16x8*)(Bd)        = cvt8(lb00, lb01, bScl0); \
    *(u16x8*)(Bd + 4096) = cvt8(lb10, lb11, bScl1); \
    *(u16x8*)(Bd + 8192) = cvt8(lb20, lb21, bScl2); \
} while (0)

    const int swz  = (fr & 7) << 3;
    const int col0 = (fg << 3) ^ swz;
    const int col1 = (32 + (fg << 3)) ^ swz;
    const int aro  = ((wr << 6) + fr) << 6;
    const int bro  = ((wc * 48) + fr) << 6;

#define LDA4(dst, bufo, cl) do { \
    const u16* p_ = As + (bufo) + aro + (cl); \
    dst[0] = *(const bf16x8*)(p_); \
    dst[1] = *(const bf16x8*)(p_ + 1024); \
    dst[2] = *(const bf16x8*)(p_ + 2048); \
    dst[3] = *(const bf16x8*)(p_ + 3072); } while (0)

#define LDB3(dst, bufo, cl) do { \
    const u16* p_ = Bs + (bufo) + bro + (cl); \
    dst[0] = *(const bf16x8*)(p_); \
    dst[1] = *(const bf16x8*)(p_ + 1024); \
    dst[2] = *(const bf16x8*)(p_ + 2048); } while (0)

    f32x4 acc[4][3];
    const f32x4 z = {0.f, 0.f, 0.f, 0.f};
    #pragma unroll
    for (int i = 0; i < 4; ++i)
        #pragma unroll
        for (int j = 0; j < 3; ++j) acc[i][j] = z;

    bf16x8 af0[4], af1[4], bf0[3], bf1[3];

    // prologue: tile 0 staged; tile 1 loads in flight
    ISSUE(0);
    WRITE(0);
    ISSUE(1);

    #pragma unroll 1
    for (int t = 0; t < 15; ++t) {
        const int bo  = (t & 1) ? 8192 : 0;
        const int bob = (t & 1) ? 12288 : 0;
        BAR();                      // buf[t&1] writes visible to all waves
        LDA4(af0, bo, col0); LDB3(bf0, bob, col0);
        MFMA12(af0, bf0);
        LDA4(af1, bo, col1); LDB3(bf1, bob, col1);
        MFMA12(af1, bf1);
        BAR();                      // all waves done reading buf[(t+1)&1]'s target
        WRITE((t + 1) & 1);         // compiler inserts vmcnt for the t+1 loads
        if (t < 14) ISSUE(t + 2);
    }
    BAR();
    LDA4(af0, 8192, col0); LDB3(bf0, 12288, col0);
    MFMA12(af0, bf0);
    LDA4(af1, 8192, col1); LDB3(bf1, 12288, col1);
    MFMA12(af1, bf1);

    // epilogue: C/D layout col=lane&15, row=(lane>>4)*4+reg; stride 3072
    const int ocol0 = bcol + wc * 48;
    const int orow0 = brow + (wr << 6);
    #pragma unroll
    for (int i = 0; i < 4; ++i)
        #pragma unroll
        for (int j = 0; j < 3; ++j)
            #pragma unroll
            for (int r = 0; r < 4; ++r) {
                const int row = orow0 + i * 16 + fg * 4 + r;
                const int col = ocol0 + j * 16 + fr;
                QKV[(size_t)row * 3072 + col] = f2b(acc[i][j][r]);
            }
#undef ISSUE
#undef WRITE
#undef LDA4
#undef LDB3
}

// ---------------- gemm_out: A(ab bf16) via GLL, B(Wo f32) reg-staged ----------------
// C[4096][1024] f32 = ab @ Wo^T. 128x64 tile, 512 blocks, 48 KB LDS (3 blocks/CU).
__global__ __launch_bounds__(256) void gemm_out(const u16* __restrict__ A,
                                                const float* __restrict__ Wo,
                                                float* __restrict__ C) {
    __shared__ __align__(16) u16 As[2 * 8192];   // 32 KB: [buf][128][64]
    __shared__ __align__(16) u16 Bs[2 * 4096];   // 16 KB: [buf][64][64]
    const int tid  = threadIdx.x;
    const int lane = tid & 63;
    const int wid  = tid >> 6;
    const int wr   = wid >> 1;
    const int wc   = wid & 1;
    const int fr   = lane & 15;
    const int fg   = lane >> 4;

    const int hw  = blockIdx.y * 16 + blockIdx.x;
    const int xcd = hw & 7;
    const int idx = hw >> 3;
    const int reg = xcd + ((idx >> 4) << 3);
    const int mt  = ((reg >> 2) << 2) + ((idx & 15) >> 2);
    const int nt  = ((reg & 3) << 2) + (idx & 3);
    const int brow = mt << 7;
    const int bcol = nt << 6;

    const int srow = tid >> 3;          // 0..31
    const int cg   = tid & 7;
    const int scol = ((cg ^ (srow & 7)) << 3);
    const u16* Ag = A + (size_t)(brow + srow) * 1024 + scol;   // pre-swizzled src for GLL
    const float* bSrc0 = Wo + (size_t)(bcol + srow) * 1024 + cg * 8;
    const float* bSrc1 = Wo + (size_t)(bcol + 32 + srow) * 1024 + cg * 8;
    const int bD = srow * 64 + ((cg ^ (srow & 7)) << 3);

#define OSTG_A(buf, kt, c) GLL(Ag + (size_t)(c) * 32768 + (kt) * 64, \
                               (char*)As + (buf) * 16384 + (c) * 4096 + (tid << 4))
#define OSTGA(buf, kt) do { \
        OSTG_A(buf, kt, 0); OSTG_A(buf, kt, 1); OSTG_A(buf, kt, 2); OSTG_A(buf, kt, 3); } while (0)
#define OISSUE(kt) do { \
    lb00 = *(const f32x4*)(bSrc0 + (kt) * 64); lb01 = *(const f32x4*)(bSrc0 + (kt) * 64 + 4); \
    lb10 = *(const f32x4*)(bSrc1 + (kt) * 64); lb11 = *(const f32x4*)(bSrc1 + (kt) * 64 + 4); } while (0)
#define OWRITE(bi) do { \
    u16* Bd = Bs + (bi) * 4096 + bD; \
    *(u16x8*)(Bd)        = cvt8(lb00, lb01, 1.0f); \
    *(u16x8*)(Bd + 2048) = cvt8(lb10, lb11, 1.0f); } while (0)

    const int swz  = (fr & 7) << 3;
    const int col0 = (fg << 3) ^ swz;
    const int col1 = (32 + (fg << 3)) ^ swz;
    const int aro  = ((wr << 6) + fr) << 6;
    const int bro  = ((wc << 5) + fr) << 6;

    f32x4 acc[4][2];
    const f32x4 z = {0.f, 0.f, 0.f, 0.f};
    #pragma unroll
    for (int i = 0; i < 4; ++i) { acc[i][0] = z; acc[i][1] = z; }
    f32x4 lb00, lb01, lb10, lb11;

#define OCOMP(bufo4, bufo3) do { \
        const u16* Ab = As + (bufo4); \
        const u16* Bb = Bs + (bufo3); \
        bf16x8 a0[4], a1[4], b0[2], b1[2]; \
        _Pragma("unroll") \
        for (int i = 0; i < 4; ++i) { \
            a0[i] = *(const bf16x8*)(Ab + aro + (i << 10) + col0); \
            a1[i] = *(const bf16x8*)(Ab + aro + (i << 10) + col1); \
        } \
        _Pragma("unroll") \
        for (int j = 0; j < 2; ++j) { \
            b0[j] = *(const bf16x8*)(Bb + bro + (j << 10) + col0); \
            b1[j] = *(const bf16x8*)(Bb + bro + (j << 10) + col1); \
        } \
        __builtin_amdgcn_s_setprio(1); \
        _Pragma("unroll") \
        for (int i = 0; i < 4; ++i) \
            _Pragma("unroll") \
            for (int j = 0; j < 2; ++j) { \
                acc[i][j] = __builtin_amdgcn_mfma_f32_16x16x32_bf16(a0[i], b0[j], acc[i][j], 0, 0, 0); \
                acc[i][j] = __builtin_amdgcn_mfma_f32_16x16x32_bf16(a1[i], b1[j], acc[i][j], 0, 0, 0); \
            } \
        __builtin_amdgcn_s_setprio(0); } while (0)

    // prologue
    OSTGA(0, 0); OISSUE(0);
    WAITV0();                 // A(0) in LDS; B(0) in regs
    OWRITE(0);
    OSTGA(1, 1); OISSUE(1);

    #pragma unroll 1
    for (int t = 0; t < 15; ++t) {
        const int bo4 = (t & 1) ? 8192 : 0;
        const int bo3 = (t & 1) ? 4096 : 0;
        BAR();
        OCOMP(bo4, bo3);
        BAR();
        WAITV0();             // A(t+1) landed in LDS, B(t+1) in regs
        OWRITE((t + 1) & 1);
        if (t < 14) { OSTGA(t & 1, t + 2); OISSUE(t + 2); }
    }
    BAR();
    OCOMP(8192, 4096);        // tile 15
#undef OSTG_A
#undef OSTGA
#undef OISSUE
#undef OWRITE
#undef OCOMP

    #pragma unroll
    for (int i = 0; i < 4; ++i)
        #pragma unroll
        for (int j = 0; j < 2; ++j)
            #pragma unroll
            for (int r = 0; r < 4; ++r) {
                const int row = brow + wr * 64 + i * 16 + fg * 4 + r;
                const int col = bcol + wc * 32 + j * 16 + fr;
                C[(size_t)row * 1024 + col] = acc[i][j][r];
            }
}

// ---------------- sliding-window attention (unchanged from R11) ----------------
__global__ __launch_bounds__(256) void attn_kernel(const u16* __restrict__ QKV,
                                                   u16* __restrict__ Og) {
    const int qb  = blockIdx.x;
    const int h   = blockIdx.y;
    const int tid = threadIdx.x;
    const int lane = tid & 63;
    const int w  = tid >> 6;
    const int fr = lane & 15;
    const int fg = lane >> 4;

    __shared__ __align__(16) u16 QK[64 * 72 + 128 * 72];
    __shared__ __align__(16) u16 Vt[64 * 138];
    __shared__ float Mrow[64][4];
    __shared__ float Lrow[64][4];

    u16* Qs = QK;
    u16* Ks = QK + 64 * 72;
    u16* Ps = QK;

    const u16* Qg = QKV;
    const u16* Kg = QKV + 1024;
    const u16* Vg = QKV + 2048;

    const int hoff  = h * 64;
    const int qrow0 = qb * 64;
    const int krow0 = qrow0 - 64;

    {
        const int r  = tid >> 3;
        const int c0 = (tid & 7) * 8;
        #pragma unroll
        for (int it = 0; it < 2; ++it) {
            const int row = r + it * 32;
            u16x8 val = *(const u16x8*)(Qg + (size_t)(qrow0 + row) * 3072 + hoff + c0);
            *(u16x8*)(Qs + row * 72 + c0) = val;
        }
        #pragma unroll
        for (int it = 0; it < 4; ++it) {
            const int row  = r + it * 32;
            const int grow = krow0 + row;
            u16x8 val = {0, 0, 0, 0, 0, 0, 0, 0};
            if (grow >= 0) val = *(const u16x8*)(Kg + (size_t)grow * 3072 + hoff + c0);
            *(u16x8*)(Ks + row * 72 + c0) = val;
        }
        #pragma unroll
        for (int it = 0; it < 4; ++it) {
            const int j    = r + it * 32;
            const int grow = krow0 + j;
            u16x8 val = {0, 0, 0, 0, 0, 0, 0, 0};
            if (grow >= 0) val = *(const u16x8*)(Vg + (size_t)grow * 3072 + hoff + c0);
            #pragma unroll
            for (int e = 0; e < 8; ++e) Vt[(c0 + e) * 138 + j] = val[e];
        }
    }
    __syncthreads();

    const f32x4 z = {0.f, 0.f, 0.f, 0.f};
    f32x4 s[4][2];
    #pragma unroll
    for (int i = 0; i < 4; ++i) { s[i][0] = z; s[i][1] = z; }
    #pragma unroll
    for (int kk = 0; kk < 2; ++kk) {
        const int k0 = kk * 32 + fg * 8;
        bf16x8 aq[4];
        #pragma unroll
        for (int i = 0; i < 4; ++i)
            aq[i] = *(const bf16x8*)(Qs + (i * 16 + fr) * 72 + k0);
        #pragma unroll
        for (int n = 0; n < 2; ++n) {
            const bf16x8 bk = *(const bf16x8*)(Ks + (w * 32 + n * 16 + fr) * 72 + k0);
            #pragma unroll
            for (int i = 0; i < 4; ++i)
                s[i][n] = __builtin_amdgcn_mfma_f32_16x16x32_bf16(aq[i], bk, s[i][n], 0, 0, 0);
        }
    }

    #pragma unroll
    for (int i = 0; i < 4; ++i) {
        #pragma unroll
        for (int r = 0; r < 4; ++r) {
            const int irow = i * 16 + fg * 4 + r;
            float mx = -3.0e38f;
            #pragma unroll
            for (int n = 0; n < 2; ++n) {
                const int jcol = w * 32 + n * 16 + fr;
                const bool valid = (jcol >= irow + 1) && (jcol <= irow + 64) && (krow0 + jcol >= 0);
                const float v = valid ? s[i][n][r] : -3.0e38f;
                s[i][n][r] = v;
                mx = fmaxf(mx, v);
            }
            #pragma unroll
            for (int d = 1; d < 16; d <<= 1) mx = fmaxf(mx, __shfl_xor(mx, d));
            if (fr == 0) Mrow[irow][w] = mx;
        }
    }
    __syncthreads();

    #pragma unroll
    for (int i = 0; i < 4; ++i) {
        #pragma unroll
        for (int r = 0; r < 4; ++r) {
            const int irow = i * 16 + fg * 4 + r;
            const float M = fmaxf(fmaxf(Mrow[irow][0], Mrow[irow][1]),
                                  fmaxf(Mrow[irow][2], Mrow[irow][3]));
            float sum = 0.f;
            #pragma unroll
            for (int n = 0; n < 2; ++n) {
                const float v = s[i][n][r];
                const float p = (v > -1.0e38f) ? __expf(v - M) : 0.f;
                sum += p;
                Ps[irow * 136 + (w * 32 + n * 16 + fr)] = f2b(p);
            }
            #pragma unroll
            for (int d = 1; d < 16; d <<= 1) sum += __shfl_xor(sum, d);
            if (fr == 0) Lrow[irow][w] = sum;
        }
    }
    __syncthreads();

    f32x4 o[4] = {z, z, z, z};
    #pragma unroll
    for (int ks = 0; ks < 4; ++ks) {
        const int k0 = ks * 32 + fg * 8;
        const bf16x8 ap = *(const bf16x8*)(Ps + (w * 16 + fr) * 136 + k0);
        #pragma unroll
        for (int n = 0; n < 4; ++n) {
            const bf16x8 bv = *(const bf16x8*)(Vt + (n * 16 + fr) * 138 + k0);
            o[n] = __builtin_amdgcn_mfma_f32_16x16x32_bf16(ap, bv, o[n], 0, 0, 0);
        }
    }

    #pragma unroll
    for (int r = 0; r < 4; ++r) {
        const int irow = w * 16 + fg * 4 + r;
        const float L = Lrow[irow][0] + Lrow[irow][1] + Lrow[irow][2] + Lrow[irow][3];
        const float rl = 1.0f / L;
        #pragma unroll
        for (int n = 0; n < 4; ++n)
            Og[(size_t)(qrow0 + irow) * DM + hoff + n * 16 + fr] = f2b(o[n][r] * rl);
    }
}

extern "C" void kernel_launch(void* const* d_in, const int* in_sizes, int n_in,
                              void* d_out, int out_size, void* d_ws, size_t ws_size,
                              hipStream_t stream) {
    (void)in_sizes; (void)n_in; (void)out_size; (void)ws_size;
    const float* x  = (const float*)d_in[0];
    const float* Wq = (const float*)d_in[1];
    const float* Wk = (const float*)d_in[2];
    const float* Wv = (const float*)d_in[3];
    const float* Wo = (const float*)d_in[4];
    float* out = (float*)d_out;

    char* ws = (char*)d_ws;
    u16* qkvb = (u16*)(ws);                             // 24 MB [4096][3072] (Q|K|V)
    u16* ab   = (u16*)(ws + ((size_t)24 << 20));        // 8 MB  attention output

    gemm_qkv8<<<dim3(16, 32), 512, 0, stream>>>(x, Wq, Wk, Wv, qkvb);
    attn_kernel<<<dim3(64, 16), 256, 0, stream>>>(qkvb, ab);
    gemm_out<<<dim3(16, 32), 256, 0, stream>>>(ab, Wo, out);
}

// Round 13
// 79.723 us; speedup vs baseline: 1.2571x; 1.2571x over previous
//
#include <hip/hip_runtime.h>
#include <cstdint>

typedef unsigned short u16;
using bf16x8 = __attribute__((ext_vector_type(8))) short;
using u16x8  = __attribute__((ext_vector_type(8))) unsigned short;
using f32x4  = __attribute__((ext_vector_type(4))) float;

#define DM 1024

__device__ __forceinline__ u16 f2b(float f) {
    union { float f; unsigned u; } v; v.f = f;
    unsigned r = v.u + 0x7FFFu + ((v.u >> 16) & 1u);   // round-to-nearest-even
    return (u16)(r >> 16);
}

#define GLL(gp, lp) __builtin_amdgcn_global_load_lds( \
    (const __attribute__((address_space(1))) void*)(uintptr_t)(gp), \
    (__attribute__((address_space(3))) void*)(unsigned)(uintptr_t)(lp), 16, 0, 0)

#define BAR()    __builtin_amdgcn_s_barrier()
#define WAITV6() asm volatile("s_waitcnt vmcnt(6)" ::: "memory")
#define WAITV5() asm volatile("s_waitcnt vmcnt(5)" ::: "memory")
#define WAITV0() asm volatile("s_waitcnt vmcnt(0)" ::: "memory")

// ---------------- fused f32 -> bf16 convert for all 5 inputs ----------------
// Wq is pre-scaled by 1/8 (exact in bf16) so attn needs no Q rescale.
__global__ __launch_bounds__(256) void cvt_all(const float* __restrict__ x,
                                               const float* __restrict__ Wq,
                                               const float* __restrict__ Wk,
                                               const float* __restrict__ Wv,
                                               const float* __restrict__ Wo,
                                               u16* __restrict__ xb,
                                               u16* __restrict__ wqkv,
                                               u16* __restrict__ wob) {
    size_t v = ((size_t)blockIdx.x * 256 + threadIdx.x) << 3;
    const float* src; u16* dst; size_t off; float sc = 1.0f;
    if (v < (size_t)4194304) { src = x; dst = xb; off = v; }
    else {
        size_t w = v - 4194304; int s = (int)(w >> 20); off = w & 1048575;
        src = (s == 0) ? Wq : (s == 1) ? Wk : (s == 2) ? Wv : Wo;
        dst = (s < 3) ? (wqkv + ((size_t)s << 20)) : wob;
        if (s == 0) sc = 0.125f;
    }
    const f32x4* p = (const f32x4*)(src + off);
    f32x4 a = p[0], b = p[1];
    u16x8 o;
    o[0] = f2b(a[0] * sc); o[1] = f2b(a[1] * sc); o[2] = f2b(a[2] * sc); o[3] = f2b(a[3] * sc);
    o[4] = f2b(b[0] * sc); o[5] = f2b(b[1] * sc); o[6] = f2b(b[2] * sc); o[7] = f2b(b[3] * sc);
    *(u16x8*)(dst + off) = o;
}

// ---------------- qkv GEMM: 128x192 tile, BK=64, 80KB LDS -> 2 blocks/CU ----------------
// C[4096][3072] = A @ Wqkv^T (stride 3072). 512 threads = 8 waves (2M x 4N);
// wave owns 64x48. Grid 32x16 = 512 blocks (2/CU) for cross-block latency hiding.
// Per K-tile: vmcnt(5) -> bar -> {7 ds_read + 12 MFMA} x2 -> bar -> stage t+2 (5 GLL).
#define MROW3(af_, bf_, d) \
    acc[d][0] = __builtin_amdgcn_mfma_f32_16x16x32_bf16(af_, bf_[0], acc[d][0], 0, 0, 0); \
    acc[d][1] = __builtin_amdgcn_mfma_f32_16x16x32_bf16(af_, bf_[1], acc[d][1], 0, 0, 0); \
    acc[d][2] = __builtin_amdgcn_mfma_f32_16x16x32_bf16(af_, bf_[2], acc[d][2], 0, 0, 0);

#define MFMA12(af_, bf_) do { \
    __builtin_amdgcn_s_setprio(1); \
    MROW3(af_[0], bf_, 0) \
    MROW3(af_[1], bf_, 1) \
    MROW3(af_[2], bf_, 2) \
    MROW3(af_[3], bf_, 3) \
    __builtin_amdgcn_s_setprio(0); } while (0)

__global__ __launch_bounds__(512, 4) void gemm_qkv8(const u16* __restrict__ A,
                                                    const u16* __restrict__ B,
                                                    u16* __restrict__ QKV) {
    __shared__ __align__(16) u16 As[2 * 8192];    // 32 KB: [buf][128 rows][64]
    __shared__ __align__(16) u16 Bs[2 * 12288];   // 48 KB: [buf][192 rows][64]
    const int tid  = threadIdx.x;
    const int lane = tid & 63;
    const int wid  = tid >> 6;
    const int wr   = wid >> 2;          // 0..1
    const int wc   = wid & 3;           // 0..3
    const int fr   = lane & 15;
    const int fg   = lane >> 4;

    // 2D XCD-chunked bijective mapping: 32x16 tiles, regions of 4Mx4N.
    const int hw  = blockIdx.y * 16 + blockIdx.x;    // 0..511
    const int xcd = hw & 7;
    const int idx = hw >> 3;                          // 0..63
    const int reg = xcd + ((idx >> 4) << 3);          // 0..31
    const int mt  = ((reg >> 2) << 2) + ((idx & 15) >> 2);  // 0..31
    const int nt  = ((reg & 3) << 2) + (idx & 3);           // 0..15
    const int brow = mt << 7;           // M-tile * 128
    const int bcol = nt * 192;

    const int srow = tid >> 3;                           // 0..63
    const int scol = ((tid & 7) ^ (srow & 7)) << 3;      // pre-swizzled source col
    const u16* Ag = A + (size_t)(brow + srow) * 1024 + scol;
    const u16* Bg = B + (size_t)(bcol + srow) * 1024 + scol;

// chunk = 64 rows x 64 cols x 2B = 8 KB = 512 threads x 16B; wave-uniform dest + lane*16
#define STG_A(buf, kt, c) GLL(Ag + (size_t)(c) * 65536 + (kt) * 64, \
                              (char*)As + (buf) * 16384 + (c) * 8192 + (wid << 10))
#define STG_B(buf, kt, c) GLL(Bg + (size_t)(c) * 65536 + (kt) * 64, \
                              (char*)Bs + (buf) * 24576 + (c) * 8192 + (wid << 10))
#define STG(buf, kt) do { \
        STG_A(buf, kt, 0); STG_A(buf, kt, 1); \
        STG_B(buf, kt, 0); STG_B(buf, kt, 1); STG_B(buf, kt, 2); } while (0)

    const int swz  = (fr & 7) << 3;
    const int col0 = (fg << 3) ^ swz;          // k-step 0
    const int col1 = (32 + (fg << 3)) ^ swz;   // k-step 1
    const int aro  = ((wr << 6) + fr) << 6;    // (wr*64+fr)*64
    const int bro  = ((wc * 48) + fr) << 6;    // (wc*48+fr)*64

#define LDA4(dst, bufo, cl) do { \
    const u16* p_ = As + (bufo) + aro + (cl); \
    dst[0] = *(const bf16x8*)(p_); \
    dst[1] = *(const bf16x8*)(p_ + 1024); \
    dst[2] = *(const bf16x8*)(p_ + 2048); \
    dst[3] = *(const bf16x8*)(p_ + 3072); } while (0)

#define LDB3(dst, bufo, cl) do { \
    const u16* p_ = Bs + (bufo) + bro + (cl); \
    dst[0] = *(const bf16x8*)(p_); \
    dst[1] = *(const bf16x8*)(p_ + 1024); \
    dst[2] = *(const bf16x8*)(p_ + 2048); } while (0)

    f32x4 acc[4][3];
    const f32x4 z = {0.f, 0.f, 0.f, 0.f};
    #pragma unroll
    for (int i = 0; i < 4; ++i)
        #pragma unroll
        for (int j = 0; j < 3; ++j) acc[i][j] = z;

    bf16x8 af0[4], af1[4], bf0[3], bf1[3];

    // prologue: stage K-tiles 0 and 1 (10 loads in flight)
    STG(0, 0);
    STG(1, 1);

    #pragma unroll 1
    for (int t = 0; t < 14; ++t) {
        const int bo  = (t & 1) ? 8192 : 0;
        const int bob = (t & 1) ? 12288 : 0;
        WAITV5();            // tile t landed; tile t+1's 5 stay in flight
        BAR();
        LDA4(af0, bo, col0); LDB3(bf0, bob, col0);
        MFMA12(af0, bf0);
        LDA4(af1, bo, col1); LDB3(bf1, bob, col1);
        MFMA12(af1, bf1);
        BAR();               // all waves done reading this buf
        STG(t & 1, t + 2);
    }
    WAITV5(); BAR();
    LDA4(af0, 0, col0); LDB3(bf0, 0, col0);
    MFMA12(af0, bf0);
    LDA4(af1, 0, col1); LDB3(bf1, 0, col1);
    MFMA12(af1, bf1);
    WAITV0(); BAR();
    LDA4(af0, 8192, col0); LDB3(bf0, 12288, col0);
    MFMA12(af0, bf0);
    LDA4(af1, 8192, col1); LDB3(bf1, 12288, col1);
    MFMA12(af1, bf1);

    // epilogue: C/D layout col=lane&15, row=(lane>>4)*4+reg; stride 3072
    const int ocol0 = bcol + wc * 48;
    const int orow0 = brow + (wr << 6);
    #pragma unroll
    for (int i = 0; i < 4; ++i)
        #pragma unroll
        for (int j = 0; j < 3; ++j)
            #pragma unroll
            for (int r = 0; r < 4; ++r) {
                const int row = orow0 + i * 16 + fg * 4 + r;
                const int col = ocol0 + j * 16 + fr;
                QKV[(size_t)row * 3072 + col] = f2b(acc[i][j][r]);
            }
#undef STG_A
#undef STG_B
#undef STG
#undef LDA4
#undef LDB3
}

// ---------------- gemm_out: 128x64 tile, counted-vmcnt 2-barrier loop ----------------
__global__ __launch_bounds__(256) void gemm_out(const u16* __restrict__ A,
                                                const u16* __restrict__ B,
                                                float* __restrict__ C) {
    __shared__ __align__(16) u16 As[2 * 8192];   // 32 KB: [buf][128][64]
    __shared__ __align__(16) u16 Bs[2 * 4096];   // 16 KB: [buf][64][64]
    const int tid  = threadIdx.x;
    const int lane = tid & 63;
    const int wid  = tid >> 6;
    const int wr   = wid >> 1;
    const int wc   = wid & 1;
    const int fr   = lane & 15;
    const int fg   = lane >> 4;

    const int hw  = blockIdx.y * 16 + blockIdx.x;
    const int xcd = hw & 7;
    const int idx = hw >> 3;
    const int reg = xcd + ((idx >> 4) << 3);
    const int mt  = ((reg >> 2) << 2) + ((idx & 15) >> 2);
    const int nt  = ((reg & 3) << 2) + (idx & 3);
    const int brow = mt << 7;
    const int bcol = nt << 6;

    const int srow = tid >> 3;
    const int scol = ((tid & 7) ^ (srow & 7)) << 3;
    const u16* Ag = A + (size_t)(brow + srow) * 1024 + scol;
    const u16* Bg = B + (size_t)(bcol + srow) * 1024 + scol;

#define OSTG_A(buf, kt, c) GLL(Ag + (size_t)(c) * 32768 + (kt) * 64, \
                               (char*)As + (buf) * 16384 + (c) * 4096 + (tid << 4))
#define OSTG_B(buf, kt, c) GLL(Bg + (size_t)(c) * 32768 + (kt) * 64, \
                               (char*)Bs + (buf) * 8192 + (c) * 4096 + (tid << 4))
#define OSTG(buf, kt) do { \
        OSTG_A(buf, kt, 0); OSTG_A(buf, kt, 1); OSTG_A(buf, kt, 2); OSTG_A(buf, kt, 3); \
        OSTG_B(buf, kt, 0); OSTG_B(buf, kt, 1); } while (0)

    const int swz  = (fr & 7) << 3;
    const int col0 = (fg << 3) ^ swz;
    const int col1 = (32 + (fg << 3)) ^ swz;
    const int aro  = ((wr << 6) + fr) << 6;
    const int bro  = ((wc << 5) + fr) << 6;

    f32x4 acc[4][2];
    const f32x4 z = {0.f, 0.f, 0.f, 0.f};
    #pragma unroll
    for (int i = 0; i < 4; ++i) { acc[i][0] = z; acc[i][1] = z; }

#define OCOMP(bufo4, bufo3) do { \
        const u16* Ab = As + (bufo4); \
        const u16* Bb = Bs + (bufo3); \
        bf16x8 a0[4], a1[4], b0[2], b1[2]; \
        _Pragma("unroll") \
        for (int i = 0; i < 4; ++i) { \
            a0[i] = *(const bf16x8*)(Ab + aro + (i << 10) + col0); \
            a1[i] = *(const bf16x8*)(Ab + aro + (i << 10) + col1); \
        } \
        _Pragma("unroll") \
        for (int j = 0; j < 2; ++j) { \
            b0[j] = *(const bf16x8*)(Bb + bro + (j << 10) + col0); \
            b1[j] = *(const bf16x8*)(Bb + bro + (j << 10) + col1); \
        } \
        __builtin_amdgcn_s_setprio(1); \
        _Pragma("unroll") \
        for (int i = 0; i < 4; ++i) \
            _Pragma("unroll") \
            for (int j = 0; j < 2; ++j) { \
                acc[i][j] = __builtin_amdgcn_mfma_f32_16x16x32_bf16(a0[i], b0[j], acc[i][j], 0, 0, 0); \
                acc[i][j] = __builtin_amdgcn_mfma_f32_16x16x32_bf16(a1[i], b1[j], acc[i][j], 0, 0, 0); \
            } \
        __builtin_amdgcn_s_setprio(0); } while (0)

    OSTG(0, 0);
    OSTG(1, 1);

    #pragma unroll 1
    for (int t = 0; t < 14; ++t) {
        const int bo4 = (t & 1) ? 8192 : 0;
        const int bo3 = (t & 1) ? 4096 : 0;
        WAITV6();
        BAR();
        OCOMP(bo4, bo3);
        BAR();
        OSTG(t & 1, t + 2);
    }
    WAITV6(); BAR();
    OCOMP(0, 0);
    WAITV0(); BAR();
    OCOMP(8192, 4096);
#undef OSTG_A
#undef OSTG_B
#undef OSTG
#undef OCOMP

    #pragma unroll
    for (int i = 0; i < 4; ++i)
        #pragma unroll
        for (int j = 0; j < 2; ++j)
            #pragma unroll
            for (int r = 0; r < 4; ++r) {
                const int row = brow + wr * 64 + i * 16 + fg * 4 + r;
                const int col = bcol + wc * 32 + j * 16 + fr;
                C[(size_t)row * 1024 + col] = acc[i][j][r];
            }
}

// ---------------- sliding-window attention ----------------
// Q/K/V in one [4096][3072] buffer (col blocks 0/1024/2048); Q pre-scaled via Wq.
__global__ __launch_bounds__(256) void attn_kernel(const u16* __restrict__ QKV,
                                                   u16* __restrict__ Og) {
    const int qb  = blockIdx.x;
    const int h   = blockIdx.y;
    const int tid = threadIdx.x;
    const int lane = tid & 63;
    const int w  = tid >> 6;
    const int fr = lane & 15;
    const int fg = lane >> 4;

    __shared__ __align__(16) u16 QK[64 * 72 + 128 * 72];
    __shared__ __align__(16) u16 Vt[64 * 138];
    __shared__ float Mrow[64][4];
    __shared__ float Lrow[64][4];

    u16* Qs = QK;
    u16* Ks = QK + 64 * 72;
    u16* Ps = QK;

    const u16* Qg = QKV;
    const u16* Kg = QKV + 1024;
    const u16* Vg = QKV + 2048;

    const int hoff  = h * 64;
    const int qrow0 = qb * 64;
    const int krow0 = qrow0 - 64;

    {
        const int r  = tid >> 3;
        const int c0 = (tid & 7) * 8;
        #pragma unroll
        for (int it = 0; it < 2; ++it) {
            const int row = r + it * 32;
            u16x8 val = *(const u16x8*)(Qg + (size_t)(qrow0 + row) * 3072 + hoff + c0);
            *(u16x8*)(Qs + row * 72 + c0) = val;
        }
        #pragma unroll
        for (int it = 0; it < 4; ++it) {
            const int row  = r + it * 32;
            const int grow = krow0 + row;
            u16x8 val = {0, 0, 0, 0, 0, 0, 0, 0};
            if (grow >= 0) val = *(const u16x8*)(Kg + (size_t)grow * 3072 + hoff + c0);
            *(u16x8*)(Ks + row * 72 + c0) = val;
        }
        #pragma unroll
        for (int it = 0; it < 4; ++it) {
            const int j    = r + it * 32;
            const int grow = krow0 + j;
            u16x8 val = {0, 0, 0, 0, 0, 0, 0, 0};
            if (grow >= 0) val = *(const u16x8*)(Vg + (size_t)grow * 3072 + hoff + c0);
            #pragma unroll
            for (int e = 0; e < 8; ++e) Vt[(c0 + e) * 138 + j] = val[e];
        }
    }
    __syncthreads();

    const f32x4 z = {0.f, 0.f, 0.f, 0.f};
    f32x4 s[4][2];
    #pragma unroll
    for (int i = 0; i < 4; ++i) { s[i][0] = z; s[i][1] = z; }
    #pragma unroll
    for (int kk = 0; kk < 2; ++kk) {
        const int k0 = kk * 32 + fg * 8;
        bf16x8 aq[4];
        #pragma unroll
        for (int i = 0; i < 4; ++i)
            aq[i] = *(const bf16x8*)(Qs + (i * 16 + fr) * 72 + k0);
        #pragma unroll
        for (int n = 0; n < 2; ++n) {
            const bf16x8 bk = *(const bf16x8*)(Ks + (w * 32 + n * 16 + fr) * 72 + k0);
            #pragma unroll
            for (int i = 0; i < 4; ++i)
                s[i][n] = __builtin_amdgcn_mfma_f32_16x16x32_bf16(aq[i], bk, s[i][n], 0, 0, 0);
        }
    }

    #pragma unroll
    for (int i = 0; i < 4; ++i) {
        #pragma unroll
        for (int r = 0; r < 4; ++r) {
            const int irow = i * 16 + fg * 4 + r;
            float mx = -3.0e38f;
            #pragma unroll
            for (int n = 0; n < 2; ++n) {
                const int jcol = w * 32 + n * 16 + fr;
                const bool valid = (jcol >= irow + 1) && (jcol <= irow + 64) && (krow0 + jcol >= 0);
                const float v = valid ? s[i][n][r] : -3.0e38f;
                s[i][n][r] = v;
                mx = fmaxf(mx, v);
            }
            #pragma unroll
            for (int d = 1; d < 16; d <<= 1) mx = fmaxf(mx, __shfl_xor(mx, d));
            if (fr == 0) Mrow[irow][w] = mx;
        }
    }
    __syncthreads();

    #pragma unroll
    for (int i = 0; i < 4; ++i) {
        #pragma unroll
        for (int r = 0; r < 4; ++r) {
            const int irow = i * 16 + fg * 4 + r;
            const float M = fmaxf(fmaxf(Mrow[irow][0], Mrow[irow][1]),
                                  fmaxf(Mrow[irow][2], Mrow[irow][3]));
            float sum = 0.f;
            #pragma unroll
            for (int n = 0; n < 2; ++n) {
                const float v = s[i][n][r];
                const float p = (v > -1.0e38f) ? __expf(v - M) : 0.f;
                sum += p;
                Ps[irow * 136 + (w * 32 + n * 16 + fr)] = f2b(p);
            }
            #pragma unroll
            for (int d = 1; d < 16; d <<= 1) sum += __shfl_xor(sum, d);
            if (fr == 0) Lrow[irow][w] = sum;
        }
    }
    __syncthreads();

    f32x4 o[4] = {z, z, z, z};
    #pragma unroll
    for (int ks = 0; ks < 4; ++ks) {
        const int k0 = ks * 32 + fg * 8;
        const bf16x8 ap = *(const bf16x8*)(Ps + (w * 16 + fr) * 136 + k0);
        #pragma unroll
        for (int n = 0; n < 4; ++n) {
            const bf16x8 bv = *(const bf16x8*)(Vt + (n * 16 + fr) * 138 + k0);
            o[n] = __builtin_amdgcn_mfma_f32_16x16x32_bf16(ap, bv, o[n], 0, 0, 0);
        }
    }

    #pragma unroll
    for (int r = 0; r < 4; ++r) {
        const int irow = w * 16 + fg * 4 + r;
        const float L = Lrow[irow][0] + Lrow[irow][1] + Lrow[irow][2] + Lrow[irow][3];
        const float rl = 1.0f / L;
        #pragma unroll
        for (int n = 0; n < 4; ++n)
            Og[(size_t)(qrow0 + irow) * DM + hoff + n * 16 + fr] = f2b(o[n][r] * rl);
    }
}

extern "C" void kernel_launch(void* const* d_in, const int* in_sizes, int n_in,
                              void* d_out, int out_size, void* d_ws, size_t ws_size,
                              hipStream_t stream) {
    (void)in_sizes; (void)n_in; (void)out_size; (void)ws_size;
    const float* x  = (const float*)d_in[0];
    const float* Wq = (const float*)d_in[1];
    const float* Wk = (const float*)d_in[2];
    const float* Wv = (const float*)d_in[3];
    const float* Wo = (const float*)d_in[4];
    float* out = (float*)d_out;

    char* ws = (char*)d_ws;
    u16* xb   = (u16*)(ws);                             // 8 MB  [4096][1024]
    u16* Wqkv = (u16*)(ws + ((size_t)8  << 20));        // 6 MB  [3072][1024]
    u16* Wob  = (u16*)(ws + ((size_t)14 << 20));        // 2 MB
    u16* qkvb = (u16*)(ws + ((size_t)16 << 20));        // 24 MB [4096][3072] (Q|K|V)
    u16* ab   = (u16*)(ws + ((size_t)40 << 20));        // 8 MB  attention output

    cvt_all<<<4096, 256, 0, stream>>>(x, Wq, Wk, Wv, Wo, xb, Wqkv, Wob);
    gemm_qkv8<<<dim3(16, 32), 512, 0, stream>>>(xb, Wqkv, qkvb);
    attn_kernel<<<dim3(64, 16), 256, 0, stream>>>(qkvb, ab);
    gemm_out<<<dim3(16, 32), 256, 0, stream>>>(ab, Wob, out);
}

// Round 14
// 79.520 us; speedup vs baseline: 1.2603x; 1.0025x over previous
//
#include <hip/hip_runtime.h>
#include <cstdint>

typedef unsigned short u16;
using bf16x8 = __attribute__((ext_vector_type(8))) short;
using u16x8  = __attribute__((ext_vector_type(8))) unsigned short;
using f32x4  = __attribute__((ext_vector_type(4))) float;

#define DM 1024

__device__ __forceinline__ u16 f2b(float f) {
    union { float f; unsigned u; } v; v.f = f;
    unsigned r = v.u + 0x7FFFu + ((v.u >> 16) & 1u);   // round-to-nearest-even
    return (u16)(r >> 16);
}

#define GLL(gp, lp) __builtin_amdgcn_global_load_lds( \
    (const __attribute__((address_space(1))) void*)(uintptr_t)(gp), \
    (__attribute__((address_space(3))) void*)(unsigned)(uintptr_t)(lp), 16, 0, 0)

#define BAR()     __builtin_amdgcn_s_barrier()
#define WAITV10() asm volatile("s_waitcnt vmcnt(10)" ::: "memory")
#define WAITV6()  asm volatile("s_waitcnt vmcnt(6)" ::: "memory")
#define WAITV0()  asm volatile("s_waitcnt vmcnt(0)" ::: "memory")

// ---------------- fused f32 -> bf16 convert for all 5 inputs ----------------
// Wq is pre-scaled by 1/8 (exact in bf16) so attn needs no Q rescale.
__global__ __launch_bounds__(256) void cvt_all(const float* __restrict__ x,
                                               const float* __restrict__ Wq,
                                               const float* __restrict__ Wk,
                                               const float* __restrict__ Wv,
                                               const float* __restrict__ Wo,
                                               u16* __restrict__ xb,
                                               u16* __restrict__ wqkv,
                                               u16* __restrict__ wob) {
    size_t v = ((size_t)blockIdx.x * 256 + threadIdx.x) << 3;
    const float* src; u16* dst; size_t off; float sc = 1.0f;
    if (v < (size_t)4194304) { src = x; dst = xb; off = v; }
    else {
        size_t w = v - 4194304; int s = (int)(w >> 20); off = w & 1048575;
        src = (s == 0) ? Wq : (s == 1) ? Wk : (s == 2) ? Wv : Wo;
        dst = (s < 3) ? (wqkv + ((size_t)s << 20)) : wob;
        if (s == 0) sc = 0.125f;
    }
    const f32x4* p = (const f32x4*)(src + off);
    f32x4 a = p[0], b = p[1];
    u16x8 o;
    o[0] = f2b(a[0] * sc); o[1] = f2b(a[1] * sc); o[2] = f2b(a[2] * sc); o[3] = f2b(a[3] * sc);
    o[4] = f2b(b[0] * sc); o[5] = f2b(b[1] * sc); o[6] = f2b(b[2] * sc); o[7] = f2b(b[3] * sc);
    *(u16x8*)(dst + off) = o;
}

// ---------------- qkv GEMM: 128x192 tile, BK=64, 4 waves, wave owns 64x96 ----------------
// C[4096][3072] = A @ Wqkv^T (stride 3072). 256 threads = 4 waves (2M x 2N).
// 80KB LDS -> 2 blocks/CU; each SIMD hosts 1 wave of each block (overlap at barriers).
// Per-wave per K-tile: 20 ds_read_b128 feeding 48 MFMA (read/MFMA pipes balanced 480/480).
#define MROW6(af_, bf_, d) \
    acc[d][0] = __builtin_amdgcn_mfma_f32_16x16x32_bf16(af_, bf_[0], acc[d][0], 0, 0, 0); \
    acc[d][1] = __builtin_amdgcn_mfma_f32_16x16x32_bf16(af_, bf_[1], acc[d][1], 0, 0, 0); \
    acc[d][2] = __builtin_amdgcn_mfma_f32_16x16x32_bf16(af_, bf_[2], acc[d][2], 0, 0, 0); \
    acc[d][3] = __builtin_amdgcn_mfma_f32_16x16x32_bf16(af_, bf_[3], acc[d][3], 0, 0, 0); \
    acc[d][4] = __builtin_amdgcn_mfma_f32_16x16x32_bf16(af_, bf_[4], acc[d][4], 0, 0, 0); \
    acc[d][5] = __builtin_amdgcn_mfma_f32_16x16x32_bf16(af_, bf_[5], acc[d][5], 0, 0, 0);

#define MFMA24(af_, bf_) do { \
    __builtin_amdgcn_s_setprio(1); \
    MROW6(af_[0], bf_, 0) \
    MROW6(af_[1], bf_, 1) \
    MROW6(af_[2], bf_, 2) \
    MROW6(af_[3], bf_, 3) \
    __builtin_amdgcn_s_setprio(0); } while (0)

__global__ __launch_bounds__(256, 2) void gemm_qkv8(const u16* __restrict__ A,
                                                    const u16* __restrict__ B,
                                                    u16* __restrict__ QKV) {
    __shared__ __align__(16) u16 As[2 * 8192];    // 32 KB: [buf][128 rows][64]
    __shared__ __align__(16) u16 Bs[2 * 12288];   // 48 KB: [buf][192 rows][64]
    const int tid  = threadIdx.x;
    const int lane = tid & 63;
    const int wid  = tid >> 6;
    const int wr   = wid >> 1;          // 0..1 (M)
    const int wc   = wid & 1;           // 0..1 (N)
    const int fr   = lane & 15;
    const int fg   = lane >> 4;

    // 2D XCD-chunked bijective mapping: 32x16 tiles, regions of 4Mx4N.
    const int hw  = blockIdx.y * 16 + blockIdx.x;    // 0..511
    const int xcd = hw & 7;
    const int idx = hw >> 3;                          // 0..63
    const int reg = xcd + ((idx >> 4) << 3);          // 0..31
    const int mt  = ((reg >> 2) << 2) + ((idx & 15) >> 2);  // 0..31
    const int nt  = ((reg & 3) << 2) + (idx & 3);           // 0..15
    const int brow = mt << 7;           // M-tile * 128
    const int bcol = nt * 192;

    const int srow = tid >> 3;                           // 0..31
    const int scol = ((tid & 7) ^ (srow & 7)) << 3;      // pre-swizzled source col
    const u16* Ag = A + (size_t)(brow + srow) * 1024 + scol;
    const u16* Bg = B + (size_t)(bcol + srow) * 1024 + scol;

// chunk = 32 rows x 64 cols x 2B = 4 KB = 256 threads x 16B; wave-uniform dest + lane*16
#define STG_A(buf, kt, c) GLL(Ag + (size_t)(c) * 32768 + (kt) * 64, \
                              (char*)As + (buf) * 16384 + (c) * 4096 + (tid << 4))
#define STG_B(buf, kt, c) GLL(Bg + (size_t)(c) * 32768 + (kt) * 64, \
                              (char*)Bs + (buf) * 24576 + (c) * 4096 + (tid << 4))
#define STG(buf, kt) do { \
        STG_A(buf, kt, 0); STG_A(buf, kt, 1); STG_A(buf, kt, 2); STG_A(buf, kt, 3); \
        STG_B(buf, kt, 0); STG_B(buf, kt, 1); STG_B(buf, kt, 2); \
        STG_B(buf, kt, 3); STG_B(buf, kt, 4); STG_B(buf, kt, 5); } while (0)

    const int swz  = (fr & 7) << 3;
    const int col0 = (fg << 3) ^ swz;          // k-step 0
    const int col1 = (32 + (fg << 3)) ^ swz;   // k-step 1
    const int aro  = ((wr << 6) + fr) << 6;    // (wr*64+fr)*64
    const int bro  = ((wc * 96) + fr) << 6;    // (wc*96+fr)*64

#define LDA4(dst, bufo, cl) do { \
    const u16* p_ = As + (bufo) + aro + (cl); \
    dst[0] = *(const bf16x8*)(p_); \
    dst[1] = *(const bf16x8*)(p_ + 1024); \
    dst[2] = *(const bf16x8*)(p_ + 2048); \
    dst[3] = *(const bf16x8*)(p_ + 3072); } while (0)

#define LDB6(dst, bufo, cl) do { \
    const u16* p_ = Bs + (bufo) + bro + (cl); \
    dst[0] = *(const bf16x8*)(p_); \
    dst[1] = *(const bf16x8*)(p_ + 1024); \
    dst[2] = *(const bf16x8*)(p_ + 2048); \
    dst[3] = *(const bf16x8*)(p_ + 3072); \
    dst[4] = *(const bf16x8*)(p_ + 4096); \
    dst[5] = *(const bf16x8*)(p_ + 5120); } while (0)

    f32x4 acc[4][6];
    const f32x4 z = {0.f, 0.f, 0.f, 0.f};
    #pragma unroll
    for (int i = 0; i < 4; ++i)
        #pragma unroll
        for (int j = 0; j < 6; ++j) acc[i][j] = z;

    bf16x8 af0[4], af1[4], bf0[6], bf1[6];

    // prologue: stage K-tiles 0 and 1 (20 loads in flight)
    STG(0, 0);
    STG(1, 1);

    #pragma unroll 1
    for (int t = 0; t < 14; ++t) {
        const int bo  = (t & 1) ? 8192 : 0;
        const int bob = (t & 1) ? 12288 : 0;
        WAITV10();           // tile t landed; tile t+1's 10 stay in flight
        BAR();
        LDA4(af0, bo, col0); LDB6(bf0, bob, col0);
        MFMA24(af0, bf0);
        LDA4(af1, bo, col1); LDB6(bf1, bob, col1);
        MFMA24(af1, bf1);
        BAR();               // all waves done reading this buf
        STG(t & 1, t + 2);
    }
    WAITV10(); BAR();
    LDA4(af0, 0, col0); LDB6(bf0, 0, col0);
    MFMA24(af0, bf0);
    LDA4(af1, 0, col1); LDB6(bf1, 0, col1);
    MFMA24(af1, bf1);
    WAITV0(); BAR();
    LDA4(af0, 8192, col0); LDB6(bf0, 12288, col0);
    MFMA24(af0, bf0);
    LDA4(af1, 8192, col1); LDB6(bf1, 12288, col1);
    MFMA24(af1, bf1);

    // epilogue: C/D layout col=lane&15, row=(lane>>4)*4+reg; stride 3072
    const int ocol0 = bcol + wc * 96;
    const int orow0 = brow + (wr << 6);
    #pragma unroll
    for (int i = 0; i < 4; ++i)
        #pragma unroll
        for (int j = 0; j < 6; ++j)
            #pragma unroll
            for (int r = 0; r < 4; ++r) {
                const int row = orow0 + i * 16 + fg * 4 + r;
                const int col = ocol0 + j * 16 + fr;
                QKV[(size_t)row * 3072 + col] = f2b(acc[i][j][r]);
            }
#undef STG_A
#undef STG_B
#undef STG
#undef LDA4
#undef LDB6
}

// ---------------- gemm_out: 128x64 tile, counted-vmcnt 2-barrier loop ----------------
__global__ __launch_bounds__(256) void gemm_out(const u16* __restrict__ A,
                                                const u16* __restrict__ B,
                                                float* __restrict__ C) {
    __shared__ __align__(16) u16 As[2 * 8192];   // 32 KB: [buf][128][64]
    __shared__ __align__(16) u16 Bs[2 * 4096];   // 16 KB: [buf][64][64]
    const int tid  = threadIdx.x;
    const int lane = tid & 63;
    const int wid  = tid >> 6;
    const int wr   = wid >> 1;
    const int wc   = wid & 1;
    const int fr   = lane & 15;
    const int fg   = lane >> 4;

    const int hw  = blockIdx.y * 16 + blockIdx.x;
    const int xcd = hw & 7;
    const int idx = hw >> 3;
    const int reg = xcd + ((idx >> 4) << 3);
    const int mt  = ((reg >> 2) << 2) + ((idx & 15) >> 2);
    const int nt  = ((reg & 3) << 2) + (idx & 3);
    const int brow = mt << 7;
    const int bcol = nt << 6;

    const int srow = tid >> 3;
    const int scol = ((tid & 7) ^ (srow & 7)) << 3;
    const u16* Ag = A + (size_t)(brow + srow) * 1024 + scol;
    const u16* Bg = B + (size_t)(bcol + srow) * 1024 + scol;

#define OSTG_A(buf, kt, c) GLL(Ag + (size_t)(c) * 32768 + (kt) * 64, \
                               (char*)As + (buf) * 16384 + (c) * 4096 + (tid << 4))
#define OSTG_B(buf, kt, c) GLL(Bg + (size_t)(c) * 32768 + (kt) * 64, \
                               (char*)Bs + (buf) * 8192 + (c) * 4096 + (tid << 4))
#define OSTG(buf, kt) do { \
        OSTG_A(buf, kt, 0); OSTG_A(buf, kt, 1); OSTG_A(buf, kt, 2); OSTG_A(buf, kt, 3); \
        OSTG_B(buf, kt, 0); OSTG_B(buf, kt, 1); } while (0)

    const int swz  = (fr & 7) << 3;
    const int col0 = (fg << 3) ^ swz;
    const int col1 = (32 + (fg << 3)) ^ swz;
    const int aro  = ((wr << 6) + fr) << 6;
    const int bro  = ((wc << 5) + fr) << 6;

    f32x4 acc[4][2];
    const f32x4 z = {0.f, 0.f, 0.f, 0.f};
    #pragma unroll
    for (int i = 0; i < 4; ++i) { acc[i][0] = z; acc[i][1] = z; }

#define OCOMP(bufo4, bufo3) do { \
        const u16* Ab = As + (bufo4); \
        const u16* Bb = Bs + (bufo3); \
        bf16x8 a0[4], a1[4], b0[2], b1[2]; \
        _Pragma("unroll") \
        for (int i = 0; i < 4; ++i) { \
            a0[i] = *(const bf16x8*)(Ab + aro + (i << 10) + col0); \
            a1[i] = *(const bf16x8*)(Ab + aro + (i << 10) + col1); \
        } \
        _Pragma("unroll") \
        for (int j = 0; j < 2; ++j) { \
            b0[j] = *(const bf16x8*)(Bb + bro + (j << 10) + col0); \
            b1[j] = *(const bf16x8*)(Bb + bro + (j << 10) + col1); \
        } \
        __builtin_amdgcn_s_setprio(1); \
        _Pragma("unroll") \
        for (int i = 0; i < 4; ++i) \
            _Pragma("unroll") \
            for (int j = 0; j < 2; ++j) { \
                acc[i][j] = __builtin_amdgcn_mfma_f32_16x16x32_bf16(a0[i], b0[j], acc[i][j], 0, 0, 0); \
                acc[i][j] = __builtin_amdgcn_mfma_f32_16x16x32_bf16(a1[i], b1[j], acc[i][j], 0, 0, 0); \
            } \
        __builtin_amdgcn_s_setprio(0); } while (0)

    OSTG(0, 0);
    OSTG(1, 1);

    #pragma unroll 1
    for (int t = 0; t < 14; ++t) {
        const int bo4 = (t & 1) ? 8192 : 0;
        const int bo3 = (t & 1) ? 4096 : 0;
        WAITV6();
        BAR();
        OCOMP(bo4, bo3);
        BAR();
        OSTG(t & 1, t + 2);
    }
    WAITV6(); BAR();
    OCOMP(0, 0);
    WAITV0(); BAR();
    OCOMP(8192, 4096);
#undef OSTG_A
#undef OSTG_B
#undef OSTG
#undef OCOMP

    #pragma unroll
    for (int i = 0; i < 4; ++i)
        #pragma unroll
        for (int j = 0; j < 2; ++j)
            #pragma unroll
            for (int r = 0; r < 4; ++r) {
                const int row = brow + wr * 64 + i * 16 + fg * 4 + r;
                const int col = bcol + wc * 32 + j * 16 + fr;
                C[(size_t)row * 1024 + col] = acc[i][j][r];
            }
}

// ---------------- sliding-window attention ----------------
// Q/K/V in one [4096][3072] buffer (col blocks 0/1024/2048); Q pre-scaled via Wq.
__global__ __launch_bounds__(256) void attn_kernel(const u16* __restrict__ QKV,
                                                   u16* __restrict__ Og) {
    const int qb  = blockIdx.x;
    const int h   = blockIdx.y;
    const int tid = threadIdx.x;
    const int lane = tid & 63;
    const int w  = tid >> 6;
    const int fr = lane & 15;
    const int fg = lane >> 4;

    __shared__ __align__(16) u16 QK[64 * 72 + 128 * 72];
    __shared__ __align__(16) u16 Vt[64 * 138];
    __shared__ float Mrow[64][4];
    __shared__ float Lrow[64][4];

    u16* Qs = QK;
    u16* Ks = QK + 64 * 72;
    u16* Ps = QK;

    const u16* Qg = QKV;
    const u16* Kg = QKV + 1024;
    const u16* Vg = QKV + 2048;

    const int hoff  = h * 64;
    const int qrow0 = qb * 64;
    const int krow0 = qrow0 - 64;

    {
        const int r  = tid >> 3;
        const int c0 = (tid & 7) * 8;
        #pragma unroll
        for (int it = 0; it < 2; ++it) {
            const int row = r + it * 32;
            u16x8 val = *(const u16x8*)(Qg + (size_t)(qrow0 + row) * 3072 + hoff + c0);
            *(u16x8*)(Qs + row * 72 + c0) = val;
        }
        #pragma unroll
        for (int it = 0; it < 4; ++it) {
            const int row  = r + it * 32;
            const int grow = krow0 + row;
            u16x8 val = {0, 0, 0, 0, 0, 0, 0, 0};
            if (grow >= 0) val = *(const u16x8*)(Kg + (size_t)grow * 3072 + hoff + c0);
            *(u16x8*)(Ks + row * 72 + c0) = val;
        }
        #pragma unroll
        for (int it = 0; it < 4; ++it) {
            const int j    = r + it * 32;
            const int grow = krow0 + j;
            u16x8 val = {0, 0, 0, 0, 0, 0, 0, 0};
            if (grow >= 0) val = *(const u16x8*)(Vg + (size_t)grow * 3072 + hoff + c0);
            #pragma unroll
            for (int e = 0; e < 8; ++e) Vt[(c0 + e) * 138 + j] = val[e];
        }
    }
    __syncthreads();

    const f32x4 z = {0.f, 0.f, 0.f, 0.f};
    f32x4 s[4][2];
    #pragma unroll
    for (int i = 0; i < 4; ++i) { s[i][0] = z; s[i][1] = z; }
    #pragma unroll
    for (int kk = 0; kk < 2; ++kk) {
        const int k0 = kk * 32 + fg * 8;
        bf16x8 aq[4];
        #pragma unroll
        for (int i = 0; i < 4; ++i)
            aq[i] = *(const bf16x8*)(Qs + (i * 16 + fr) * 72 + k0);
        #pragma unroll
        for (int n = 0; n < 2; ++n) {
            const bf16x8 bk = *(const bf16x8*)(Ks + (w * 32 + n * 16 + fr) * 72 + k0);
            #pragma unroll
            for (int i = 0; i < 4; ++i)
                s[i][n] = __builtin_amdgcn_mfma_f32_16x16x32_bf16(aq[i], bk, s[i][n], 0, 0, 0);
        }
    }

    #pragma unroll
    for (int i = 0; i < 4; ++i) {
        #pragma unroll
        for (int r = 0; r < 4; ++r) {
            const int irow = i * 16 + fg * 4 + r;
            float mx = -3.0e38f;
            #pragma unroll
            for (int n = 0; n < 2; ++n) {
                const int jcol = w * 32 + n * 16 + fr;
                const bool valid = (jcol >= irow + 1) && (jcol <= irow + 64) && (krow0 + jcol >= 0);
                const float v = valid ? s[i][n][r] : -3.0e38f;
                s[i][n][r] = v;
                mx = fmaxf(mx, v);
            }
            #pragma unroll
            for (int d = 1; d < 16; d <<= 1) mx = fmaxf(mx, __shfl_xor(mx, d));
            if (fr == 0) Mrow[irow][w] = mx;
        }
    }
    __syncthreads();

    #pragma unroll
    for (int i = 0; i < 4; ++i) {
        #pragma unroll
        for (int r = 0; r < 4; ++r) {
            const int irow = i * 16 + fg * 4 + r;
            const float M = fmaxf(fmaxf(Mrow[irow][0], Mrow[irow][1]),
                                  fmaxf(Mrow[irow][2], Mrow[irow][3]));
            float sum = 0.f;
            #pragma unroll
            for (int n = 0; n < 2; ++n) {
                const float v = s[i][n][r];
                const float p = (v > -1.0e38f) ? __expf(v - M) : 0.f;
                sum += p;
                Ps[irow * 136 + (w * 32 + n * 16 + fr)] = f2b(p);
            }
            #pragma unroll
            for (int d = 1; d < 16; d <<= 1) sum += __shfl_xor(sum, d);
            if (fr == 0) Lrow[irow][w] = sum;
        }
    }
    __syncthreads();

    f32x4 o[4] = {z, z, z, z};
    #pragma unroll
    for (int ks = 0; ks < 4; ++ks) {
        const int k0 = ks * 32 + fg * 8;
        const bf16x8 ap = *(const bf16x8*)(Ps + (w * 16 + fr) * 136 + k0);
        #pragma unroll
        for (int n = 0; n < 4; ++n) {
            const bf16x8 bv = *(const bf16x8*)(Vt + (n * 16 + fr) * 138 + k0);
            o[n] = __builtin_amdgcn_mfma_f32_16x16x32_bf16(ap, bv, o[n], 0, 0, 0);
        }
    }

    #pragma unroll
    for (int r = 0; r < 4; ++r) {
        const int irow = w * 16 + fg * 4 + r;
        const float L = Lrow[irow][0] + Lrow[irow][1] + Lrow[irow][2] + Lrow[irow][3];
        const float rl = 1.0f / L;
        #pragma unroll
        for (int n = 0; n < 4; ++n)
            Og[(size_t)(qrow0 + irow) * DM + hoff + n * 16 + fr] = f2b(o[n][r] * rl);
    }
}

extern "C" void kernel_launch(void* const* d_in, const int* in_sizes, int n_in,
                              void* d_out, int out_size, void* d_ws, size_t ws_size,
                              hipStream_t stream) {
    (void)in_sizes; (void)n_in; (void)out_size; (void)ws_size;
    const float* x  = (const float*)d_in[0];
    const float* Wq = (const float*)d_in[1];
    const float* Wk = (const float*)d_in[2];
    const float* Wv = (const float*)d_in[3];
    const float* Wo = (const float*)d_in[4];
    float* out = (float*)d_out;

    char* ws = (char*)d_ws;
    u16* xb   = (u16*)(ws);                             // 8 MB  [4096][1024]
    u16* Wqkv = (u16*)(ws + ((size_t)8  << 20));        // 6 MB  [3072][1024]
    u16* Wob  = (u16*)(ws + ((size_t)14 << 20));        // 2 MB
    u16* qkvb = (u16*)(ws + ((size_t)16 << 20));        // 24 MB [4096][3072] (Q|K|V)
    u16* ab   = (u16*)(ws + ((size_t)40 << 20));        // 8 MB  attention output

    cvt_all<<<4096, 256, 0, stream>>>(x, Wq, Wk, Wv, Wo, xb, Wqkv, Wob);
    gemm_qkv8<<<dim3(16, 32), 256, 0, stream>>>(xb, Wqkv, qkvb);
    attn_kernel<<<dim3(64, 16), 256, 0, stream>>>(qkvb, ab);
    gemm_out<<<dim3(16, 32), 256, 0, stream>>>(ab, Wob, out);
}